// Round 1
// baseline (202.743 us; speedup 1.0000x reference)
//
#include <hip/hip_runtime.h>

// Problem: B=8, L=2048, H=256. fp32 in/out.
#define B_ 8
#define L_ 2048
#define H_ 256

typedef _Float16 half8 __attribute__((ext_vector_type(8)));
typedef _Float16 half4_t __attribute__((ext_vector_type(4)));
typedef float f32x4 __attribute__((ext_vector_type(4)));

__device__ __forceinline__ float fast_tanh(float x) {
    const float e2 = __expf(2.f * x);
    return 1.f - 2.f * __builtin_amdgcn_rcpf(e2 + 1.f);
}

// ---------------------------------------------------------------------------
// prep: one block = 64 rows of text (mat=0) or opin (mat=1).
// MFMA GEMM rows@W^T (fp16 in, fp32 acc), epilogue tanh/wa reduce.
// mat=0 -> ws_st[row]; mat=1 -> ws_cm[row]={c*mult,mult} and V^T fp16 -> vtg.
// (unchanged from verified baseline)
// ---------------------------------------------------------------------------
__global__ __launch_bounds__(256, 2) void prep_kernel(
    const float* __restrict__ opin, const float* __restrict__ text,
    const int* __restrict__ pos_ids,
    const float* __restrict__ Wt, const float* __restrict__ bt,
    const float* __restrict__ Wo, const float* __restrict__ wa,
    const float* __restrict__ ba,
    float* __restrict__ ws_st, float2* __restrict__ ws_cm,
    _Float16* __restrict__ vtg)
{
    __shared__ __align__(16) _Float16 a_lds[4][8][512];  // [rowgrp][kchunk][frag-linear]
    __shared__ __align__(16) _Float16 w_lds[16][512];    // [ntile][frag-linear], per chunk

    const int tid  = threadIdx.x;
    const int lane = tid & 63;
    const int rg   = tid >> 6;                 // wave id = 16-row group
    const int mat  = blockIdx.x & 1;           // 0=text, 1=opin
    const size_t g0 = (size_t)(blockIdx.x >> 1) * 64;   // first flattened row (b*L+i)

    const float* __restrict__ src = mat ? opin : text;
    const float* __restrict__ W   = mat ? Wo   : Wt;

    // ---- stage A: 64 rows x 256 k, fp32 -> fp16, frag-linear per (rg, kc) ----
    for (int v = 0; v < 16; ++v) {
        const int idx = v * 256 + tid;      // float4 index in 64x64 grid
        const int row = idx >> 6;           // 0..63
        const int k   = (idx & 63) * 4;     // 0..252
        const float4 f = *(const float4*)(src + (g0 + row) * 256 + k);
        half4_t h = { (_Float16)f.x, (_Float16)f.y, (_Float16)f.z, (_Float16)f.w };
        const int off = ((row & 15) + 16 * ((k >> 3) & 3)) * 8 + (k & 7); // k&7 in {0,4}
        *(half4_t*)&a_lds[row >> 4][k >> 5][off] = h;
    }
    __syncthreads();

    f32x4 acc[16];
#pragma unroll
    for (int nt = 0; nt < 16; ++nt) acc[nt] = (f32x4){0.f, 0.f, 0.f, 0.f};

    for (int kc = 0; kc < 8; ++kc) {
        // stage W chunk: 256 n x 32 k
        for (int p = 0; p < 8; ++p) {
            const int n = p * 32 + (tid >> 3);
            const int k = (tid & 7) * 4;    // within chunk
            const float4 f = *(const float4*)(W + n * 256 + kc * 32 + k);
            half4_t h = { (_Float16)f.x, (_Float16)f.y, (_Float16)f.z, (_Float16)f.w };
            const int off = ((n & 15) + 16 * (k >> 3)) * 8 + (k & 7);
            *(half4_t*)&w_lds[n >> 4][off] = h;
        }
        __syncthreads();
        const half8 afrag = *(const half8*)&a_lds[rg][kc][lane * 8];
#pragma unroll
        for (int nt = 0; nt < 16; ++nt) {
            const half8 bfrag = *(const half8*)&w_lds[nt][lane * 8];
            acc[nt] = __builtin_amdgcn_mfma_f32_16x16x32_f16(afrag, bfrag, acc[nt], 0, 0, 0);
        }
        __syncthreads();
    }

    // ---- epilogue: rowsum_n( tanh(acc + bt?) * wa ) ----
    const int em = lane & 15, q = lane >> 4;
    float rowsum[4] = {0.f, 0.f, 0.f, 0.f};
#pragma unroll
    for (int nt = 0; nt < 16; ++nt) {
        const int col  = nt * 16 + em;
        const float btv = mat ? 0.f : bt[col];
        const float wav = wa[mat * 256 + col];
#pragma unroll
        for (int r = 0; r < 4; ++r)
            rowsum[r] += fast_tanh(acc[nt][r] + btv) * wav;
    }
#pragma unroll
    for (int r = 0; r < 4; ++r) {
        float s = rowsum[r];
        s += __shfl_xor(s, 1, 64);
        s += __shfl_xor(s, 2, 64);
        s += __shfl_xor(s, 4, 64);
        s += __shfl_xor(s, 8, 64);
        if (em == 0) {
            const size_t grow = g0 + rg * 16 + q * 4 + r;
            if (mat == 0) {
                ws_st[grow] = s;
            } else {
                const int p = pos_ids[grow];
                const bool isop = (p==19)|(p==20)|(p==21)|(p==33)|(p==34)|(p==35)|((p>=41)&(p<=46));
                const float mult = isop ? 8.f : 1.f;
                const float c = s + ba[0];
                ws_cm[grow] = make_float2(c * mult, mult);
            }
        }
    }

    // ---- V^T emission (opin blocks): vtg[(b*256+h)*2048 + j] fp16 ----
    if (mat == 1) {
        const int h = tid;
        const size_t b = g0 >> 11;
        const int j0 = (int)(g0 & 2047);
        const int kc = h >> 5, kq = (h >> 3) & 3, jh = h & 7;
        _Float16 vals[64];
#pragma unroll
        for (int r = 0; r < 64; ++r)
            vals[r] = a_lds[r >> 4][kc][((r & 15) + 16 * kq) * 8 + jh];
        _Float16* dst = vtg + ((b * 256 + h) * 2048 + j0);
#pragma unroll
        for (int w = 0; w < 8; ++w)
            *(half8*)(dst + w * 8) = *(half8*)&vals[w * 8];
    }
}

// ---------------------------------------------------------------------------
// attn v2: one block = (batch b, 64-row i-tile), FULL 256 h.  512 thr, 8 waves.
//  - scores computed ONCE per (i,j) (no h-half duplication)
//  - row-local softmax: row's 64 j live in 8 consecutive lanes of one wave;
//    chunk-max via 3 shfl_xor; m/alpha/z in-register; only alpha crosses waves
//  - bias via LDS table base[d]*log2e (built once); exp via raw v_exp_f32
//  - V^T B-fragments loaded DIRECTLY from global (L2/L3-resident vtg) into
//    regs, double-buffered, prefetched one chunk ahead (no vt_lds round trip)
//  - ONE __syncthreads per chunk (P and alpha double-buffered in LDS)
// ---------------------------------------------------------------------------
__global__ __launch_bounds__(512, 2) void attn_kernel(
    const float* __restrict__ ws_st, const float2* __restrict__ ws_cm,
    const _Float16* __restrict__ vtg, float* __restrict__ out)
{
    __shared__ float t_lds[2048];                           // base[d]*log2e, 8 KB
    __shared__ __align__(16) _Float16 p_lds[2][4][2][512];  // [buf][rt][ks][frag-linear]
    __shared__ float alpha_lds[2][64];
    __shared__ float z_lds[64];

    const int tid  = threadIdx.x;
    const int lane = tid & 63;
    const int wid  = tid >> 6;                // 0..7
    const int rgp  = wid & 1;                 // MFMA rows rgp*32 .. +31
    const int hq   = wid >> 1;                // MFMA cols hq*64 .. +63
    const int em   = lane & 15;
    const int q4   = lane >> 4;

    const int b  = blockIdx.x & 7;            // consecutive blocks spread batches
    const int i0 = (blockIdx.x >> 3) * 64;

    const int row = tid >> 3;                 // scoring row 0..63 (8 lanes/row)
    const int jg  = tid & 7;                  // 8-j group within chunk
    const int gi  = i0 + row;

    // ---- bias table: d==0 ? 0.5 : 1/log2(2+d), scaled by log2(e) ----
#pragma unroll
    for (int v = 0; v < 4; ++v) {
        const int d = tid * 4 + v;
        const float bv = (d == 0) ? 0.5f : 1.0f / __log2f(2.f + (float)d);
        t_lds[d] = bv * 1.44269504088896f;
    }

    const float sti = ws_st[b * 2048 + gi];
    // per-lane V^T base: hcol = hq*64 + ht*16 + em, k-slice q4 -> j = ks*32+q4*8+v
    const _Float16* __restrict__ vb =
        vtg + ((size_t)(b * 256 + hq * 64 + em)) * 2048 + q4 * 8;

    f32x4 acc[2][4];
#pragma unroll
    for (int rt = 0; rt < 2; ++rt)
#pragma unroll
        for (int ht = 0; ht < 4; ++ht) acc[rt][ht] = (f32x4){0.f, 0.f, 0.f, 0.f};
    float m_run = -1e30f;
    float zacc  = 0.f;

    // prologue: issue chunk-0 B-fragments (drained at first barrier)
    half8 bfA[2][4], bfB[2][4];
#pragma unroll
    for (int ks = 0; ks < 2; ++ks)
#pragma unroll
        for (int ht = 0; ht < 4; ++ht)
            bfA[ks][ht] = *(const half8*)(vb + ht * 32768 + ks * 32);

    __syncthreads();   // t_lds ready

    auto body = [&](const int kc, const int buf,
                    half8 (&cur)[2][4], half8 (&nxt)[2][4]) {
        const int j0 = kc * 64;

        // --- scores: 8 j per lane, bias from table ---
        float s_arr[8];
        float mx = -1e30f;
        {
            const float4* __restrict__ cmp =
                (const float4*)(ws_cm + b * 2048 + j0 + jg * 8);
#pragma unroll
            for (int w = 0; w < 4; ++w) {
                const float4 c4 = cmp[w];          // {c0*m0, m0, c1*m1, m1}
                const int jj = j0 + jg * 8 + w * 2;
                int d0 = gi - jj;     d0 = d0 < 0 ? -d0 : d0;
                int d1 = gi - jj - 1; d1 = d1 < 0 ? -d1 : d1;
                const float s0 = (sti * c4.y + c4.x) * t_lds[d0];
                const float s1 = (sti * c4.w + c4.z) * t_lds[d1];
                s_arr[2 * w]     = s0;
                s_arr[2 * w + 1] = s1;
                mx = fmaxf(mx, fmaxf(s0, s1));
            }
        }
        // row max across the row's 8 lanes (consecutive, 8-aligned)
        mx = fmaxf(mx, __shfl_xor(mx, 1, 64));
        mx = fmaxf(mx, __shfl_xor(mx, 2, 64));
        mx = fmaxf(mx, __shfl_xor(mx, 4, 64));

        const float m_new = fmaxf(m_run, mx);
        const float alpha = __builtin_amdgcn_exp2f(m_run - m_new); // ==1 if no update
        float zl = 0.f;
        half8 pv;
#pragma unroll
        for (int v = 0; v < 8; ++v) {
            const float p = __builtin_amdgcn_exp2f(s_arr[v] - m_new);
            zl += p;
            pv[v] = (_Float16)p;
        }
        zacc  = zacc * alpha + zl;
        m_run = m_new;

        // P frag-linear: row rt*16+mrow, j = ks*32 + kq*8 + v
        *(half8*)&p_lds[buf][row >> 4][jg >> 2][((row & 15) + 16 * (jg & 3)) * 8] = pv;
        if (jg == 0) alpha_lds[buf][row] = alpha;

        __syncthreads();   // the ONLY barrier per chunk

        // --- prefetch next chunk's B-fragments (drained at next barrier) ---
        if (kc < 31) {
#pragma unroll
            for (int ks = 0; ks < 2; ++ks)
#pragma unroll
                for (int ht = 0; ht < 4; ++ht)
                    nxt[ks][ht] = *(const half8*)(vb + ht * 32768 + (j0 + 64) + ks * 32);
        }

        // --- rescale acc by per-row alpha (broadcast reads, conflict-free) ---
        {
            float ar[2][4];
            bool upd = false;
#pragma unroll
            for (int rt = 0; rt < 2; ++rt)
#pragma unroll
                for (int r = 0; r < 4; ++r) {
                    ar[rt][r] = alpha_lds[buf][rgp * 32 + rt * 16 + q4 * 4 + r];
                    upd |= (ar[rt][r] != 1.f);
                }
            if (__any(upd)) {
#pragma unroll
                for (int rt = 0; rt < 2; ++rt)
#pragma unroll
                    for (int ht = 0; ht < 4; ++ht)
#pragma unroll
                        for (int r = 0; r < 4; ++r)
                            acc[rt][ht][r] *= ar[rt][r];
            }
        }

        // --- MFMA: P(64x64) @ V^T-cols, B-fragments already in regs ---
#pragma unroll
        for (int ks = 0; ks < 2; ++ks) {
            const half8 a0 = *(const half8*)&p_lds[buf][rgp * 2 + 0][ks][lane * 8];
            const half8 a1 = *(const half8*)&p_lds[buf][rgp * 2 + 1][ks][lane * 8];
#pragma unroll
            for (int ht = 0; ht < 4; ++ht) {
                acc[0][ht] = __builtin_amdgcn_mfma_f32_16x16x32_f16(a0, cur[ks][ht], acc[0][ht], 0, 0, 0);
                acc[1][ht] = __builtin_amdgcn_mfma_f32_16x16x32_f16(a1, cur[ks][ht], acc[1][ht], 0, 0, 0);
            }
        }
    };

    for (int kc = 0; kc < 32; kc += 2) {
        body(kc,     0, bfA, bfB);
        body(kc + 1, 1, bfB, bfA);
    }

    // --- Z finalize: reduce the row's 8 lanes, publish ---
    zacc += __shfl_xor(zacc, 1, 64);
    zacc += __shfl_xor(zacc, 2, 64);
    zacc += __shfl_xor(zacc, 4, 64);
    if (jg == 0) z_lds[row] = zacc;
    __syncthreads();

    // --- epilogue: normalize, store. C/D: col=lane&15, row=(lane>>4)*4+reg ---
#pragma unroll
    for (int rt = 0; rt < 2; ++rt) {
#pragma unroll
        for (int r = 0; r < 4; ++r) {
            const int orow = rgp * 32 + rt * 16 + q4 * 4 + r;
            const float rz = 1.f / z_lds[orow];
#pragma unroll
            for (int ht = 0; ht < 4; ++ht)
                out[((size_t)b * 2048 + i0 + orow) * 256 + hq * 64 + ht * 16 + em] =
                    acc[rt][ht][r] * rz;
        }
    }
}

// ---------------------------------------------------------------------------
extern "C" void kernel_launch(void* const* d_in, const int* in_sizes, int n_in,
                              void* d_out, int out_size, void* d_ws, size_t ws_size,
                              hipStream_t stream) {
    const float* opin  = (const float*)d_in[0];
    const float* text  = (const float*)d_in[1];
    const int* pos_ids = (const int*)d_in[2];
    const float* Wt    = (const float*)d_in[3];
    const float* bt    = (const float*)d_in[4];
    const float* Wo    = (const float*)d_in[5];
    const float* wa    = (const float*)d_in[6];
    const float* ba    = (const float*)d_in[7];
    float* out         = (float*)d_out;

    // workspace: st (64 KB) | cm (128 KB) | vtg fp16 (8 MB)
    float*  ws_st = (float*)d_ws;
    float2* ws_cm = (float2*)((char*)d_ws + 65536);
    _Float16* vtg = (_Float16*)((char*)d_ws + 65536 + 131072);

    prep_kernel<<<512, 256, 0, stream>>>(opin, text, pos_ids, Wt, bt, Wo, wa, ba,
                                         ws_st, ws_cm, vtg);
    attn_kernel<<<256, 512, 0, stream>>>(ws_st, ws_cm, vtg, out);
}